// Round 2
// baseline (1973.596 us; speedup 1.0000x reference)
//
#include <hip/hip_runtime.h>

#define NN 100000
#define NE 3200000
#define DIN 128
#define HD 64
#define DEMB 32
#define NG 256

// ---------------- degree count (incoming edges), then dinv = rsqrt(deg+1) ----
__global__ void k_deg(const int* __restrict__ dst, float* __restrict__ deg, int E) {
    int i = blockIdx.x * blockDim.x + threadIdx.x;
    int stride = gridDim.x * blockDim.x;
    for (; i < E; i += stride) {
        atomicAdd(&deg[dst[i]], 1.0f);
    }
}

__global__ void k_dinv(float* __restrict__ deg, int n) {
    int i = blockIdx.x * blockDim.x + threadIdx.x;
    if (i < n) deg[i] = rsqrtf(deg[i] + 1.0f);
}

// ---------------- GEMM: T[n][64] = X[n][K] @ W[K][64] ------------------------
// block = 256 threads: 16 col-groups (4 cols each) x 16 rows per iteration.
template <int K>
__global__ void k_gemm(const float* __restrict__ X, const float* __restrict__ W,
                       float* __restrict__ T, int n) {
    __shared__ __align__(16) float wl[K * 64];
    __shared__ __align__(16) float xs[16][K];
    int tid = threadIdx.x;
    for (int i = tid; i < K * 64; i += 256) wl[i] = W[i];
    int cg = tid & 15;        // column group: cols 4*cg .. 4*cg+3
    int rs = tid >> 4;        // row within 16-row group
    int ngrp = (n + 15) >> 4;
    for (int grp = blockIdx.x; grp < ngrp; grp += gridDim.x) {
        int row0 = grp * 16;
        __syncthreads();  // protect xs (and wl on first iter) from overwrite
        for (int i = tid; i < 16 * K; i += 256) {
            int r = i / K, c = i % K;
            int row = row0 + r;
            xs[r][c] = (row < n) ? X[(size_t)row * K + c] : 0.0f;
        }
        __syncthreads();
        float4 acc = {0.f, 0.f, 0.f, 0.f};
#pragma unroll 8
        for (int k = 0; k < K; k++) {
            float xv = xs[rs][k];
            float4 w4 = *reinterpret_cast<const float4*>(&wl[k * 64 + cg * 4]);
            acc.x += xv * w4.x;
            acc.y += xv * w4.y;
            acc.z += xv * w4.z;
            acc.w += xv * w4.w;
        }
        int row = row0 + rs;
        if (row < n) {
            *reinterpret_cast<float4*>(&T[(size_t)row * 64 + cg * 4]) = acc;
        }
    }
}

// ---------------- edge scatter: agg[dst] += T[src] * dinv[src]*dinv[dst] -----
// one wave (64 lanes) per edge; lane = channel.
__global__ void k_scatter(const int* __restrict__ src, const int* __restrict__ dst,
                          const float* __restrict__ dinv, const float* __restrict__ T,
                          float* __restrict__ agg, int E) {
    int gtid = blockIdx.x * blockDim.x + threadIdx.x;
    int lane = gtid & 63;
    int w = gtid >> 6;
    int nw = (gridDim.x * blockDim.x) >> 6;
    for (int e = w; e < E; e += nw) {
        int s = src[e];
        int d = dst[e];
        float coef = dinv[s] * dinv[d];
        float v = T[(size_t)s * 64 + lane] * coef;
        atomicAdd(&agg[(size_t)d * 64 + lane], v);
    }
}

// ---------------- self-loop + bias + relu, in place on agg -------------------
__global__ void k_selfrelu(float* __restrict__ agg, const float* __restrict__ T,
                           const float* __restrict__ dinv, const float* __restrict__ b, int n) {
    int i = blockIdx.x * blockDim.x + threadIdx.x;
    int total = n * 64;
    int stride = gridDim.x * blockDim.x;
    for (; i < total; i += stride) {
        int node = i >> 6, c = i & 63;
        float dv = dinv[node];
        float v = agg[i] + T[i] * dv * dv + b[c];
        agg[i] = v > 0.f ? v : 0.f;
    }
}

// ---------------- mean-pool accumulate ---------------------------------------
__global__ void k_pool(const float* __restrict__ h, const int* __restrict__ batch,
                       float* __restrict__ sums, float* __restrict__ cnt, int n) {
    int gtid = blockIdx.x * blockDim.x + threadIdx.x;
    int lane = gtid & 63;
    int w = gtid >> 6;
    int nw = (gridDim.x * blockDim.x) >> 6;
    for (int node = w; node < n; node += nw) {
        int g = batch[node];
        atomicAdd(&sums[g * 64 + lane], h[(size_t)node * 64 + lane]);
        if (lane == 0) atomicAdd(&cnt[g], 1.0f);
    }
}

// ---------------- head: out[g] = (sums[g]/cnt[g]) @ Wl + bl ------------------
__global__ void k_final(const float* __restrict__ sums, const float* __restrict__ cnt,
                        const float* __restrict__ Wl, const float* __restrict__ bl,
                        float* __restrict__ out) {
    __shared__ float pooled[64];
    int g = blockIdx.x;
    int t = threadIdx.x;
    float c = cnt[g];
    c = c < 1.0f ? 1.0f : c;
    pooled[t] = sums[g * 64 + t] / c;
    __syncthreads();
    if (t < 32) {
        float acc = bl[t];
#pragma unroll 8
        for (int k = 0; k < 64; k++) acc += pooled[k] * Wl[k * 32 + t];
        out[g * 32 + t] = acc;
    }
}

extern "C" void kernel_launch(void* const* d_in, const int* in_sizes, int n_in,
                              void* d_out, int out_size, void* d_ws, size_t ws_size,
                              hipStream_t stream) {
    const float* x = (const float*)d_in[0];
    const int* ei = (const int*)d_in[1];      // [2, E] int32 (harness narrows int64 -> int32)
    const int* batch = (const int*)d_in[2];   // [N] int32
    const float* W1 = (const float*)d_in[4];
    const float* b1 = (const float*)d_in[5];
    const float* W2 = (const float*)d_in[6];
    const float* b2 = (const float*)d_in[7];
    const float* Wl = (const float*)d_in[8];
    const float* bl = (const float*)d_in[9];
    float* out = (float*)d_out;

    const int* esrc = ei;
    const int* edst = ei + NE;

    // workspace layout (byte offsets, 256-aligned)
    char* ws = (char*)d_ws;
    size_t off = 0;
    auto alloc = [&](size_t bytes) {
        void* p = ws + off;
        off += (bytes + 255) & ~size_t(255);
        return p;
    };
    float* dinv = (float*)alloc((size_t)NN * 4);
    float* tbuf = (float*)alloc((size_t)NN * HD * 4);
    float* agg  = (float*)alloc((size_t)NN * HD * 4);
    float* sums = (float*)alloc((size_t)NG * HD * 4);  // sums then cnt contiguous
    float* cnt  = (float*)alloc((size_t)NG * 4);

    // 1. degree -> dinv
    hipMemsetAsync(dinv, 0, (size_t)NN * 4, stream);
    k_deg<<<2048, 256, 0, stream>>>(edst, dinv, NE);
    k_dinv<<<(NN + 255) / 256, 256, 0, stream>>>(dinv, NN);

    // 2. layer 1
    k_gemm<DIN><<<512, 256, 0, stream>>>(x, W1, tbuf, NN);
    hipMemsetAsync(agg, 0, (size_t)NN * HD * 4, stream);
    k_scatter<<<2048, 256, 0, stream>>>(esrc, edst, dinv, tbuf, agg, NE);
    k_selfrelu<<<2048, 256, 0, stream>>>(agg, tbuf, dinv, b1, NN);
    // h1 now lives in agg

    // 3. layer 2
    k_gemm<HD><<<512, 256, 0, stream>>>(agg, W2, tbuf, NN);
    hipMemsetAsync(agg, 0, (size_t)NN * HD * 4, stream);
    k_scatter<<<2048, 256, 0, stream>>>(esrc, edst, dinv, tbuf, agg, NE);
    k_selfrelu<<<2048, 256, 0, stream>>>(agg, tbuf, dinv, b2, NN);
    // h2 now lives in agg

    // 4. pool + head
    hipMemsetAsync(sums, 0, (size_t)(NG * HD + NG) * 4, stream);
    k_pool<<<1024, 256, 0, stream>>>(agg, batch, sums, cnt, NN);
    k_final<<<NG, 64, 0, stream>>>(sums, cnt, Wl, bl, out);
}

// Round 3
// 1290.270 us; speedup vs baseline: 1.5296x; 1.5296x over previous
//
#include <hip/hip_runtime.h>

#define NN 100000
#define NE 3200000
#define DIN 128
#define HD 64
#define DEMB 32
#define NG 256
#define NBLK ((NN + 1023) / 1024)   // scan blocks = 98

// ---------------- int degree histogram over dst -------------------------------
__global__ void k_hist(const int* __restrict__ dst, int* __restrict__ degi, int E) {
    int i = blockIdx.x * blockDim.x + threadIdx.x;
    int stride = gridDim.x * blockDim.x;
    for (; i < E; i += stride) atomicAdd(&degi[dst[i]], 1);
}

// ---------------- dinv = rsqrt(deg+1) ----------------------------------------
__global__ void k_dinv(const int* __restrict__ degi, float* __restrict__ dinv, int n) {
    int i = blockIdx.x * blockDim.x + threadIdx.x;
    if (i < n) dinv[i] = rsqrtf((float)degi[i] + 1.0f);
}

// ---------------- scan pass 1: per-1024-block exclusive scan ------------------
__global__ __launch_bounds__(1024) void k_scan1(const int* __restrict__ degi,
                                                int* __restrict__ part,
                                                int* __restrict__ bsum, int n) {
    __shared__ int s[1024];
    int t = threadIdx.x;
    int idx = blockIdx.x * 1024 + t;
    int v = (idx < n) ? degi[idx] : 0;
    s[t] = v;
    __syncthreads();
    for (int off = 1; off < 1024; off <<= 1) {
        int add = (t >= off) ? s[t - off] : 0;
        __syncthreads();
        s[t] += add;
        __syncthreads();
    }
    if (idx < n) part[idx] = s[t] - v;          // exclusive
    if (t == 1023) bsum[blockIdx.x] = s[t];     // block total
}

// ---------------- scan pass 2: serial scan of block sums ----------------------
__global__ void k_scan2(const int* __restrict__ bsum, int* __restrict__ boff, int nb) {
    if (threadIdx.x == 0 && blockIdx.x == 0) {
        int acc = 0;
        for (int b = 0; b < nb; b++) { boff[b] = acc; acc += bsum[b]; }
        boff[nb] = acc;   // grand total = E
    }
}

// ---------------- scan pass 3: rowptr + cursor copy ---------------------------
__global__ void k_scan3(const int* __restrict__ part, const int* __restrict__ boff,
                        int* __restrict__ rowptr, int* __restrict__ cursor, int n) {
    int idx = blockIdx.x * blockDim.x + threadIdx.x;
    if (idx < n) {
        int v = part[idx] + boff[idx >> 10];
        rowptr[idx] = v;
        cursor[idx] = v;
    }
    if (idx == n) rowptr[n] = boff[NBLK];
}

// ---------------- counting-sort bucket: ssrc sorted by dst --------------------
__global__ void k_bucket(const int* __restrict__ src, const int* __restrict__ dst,
                         int* __restrict__ cursor, int* __restrict__ ssrc, int E) {
    int i = blockIdx.x * blockDim.x + threadIdx.x;
    int stride = gridDim.x * blockDim.x;
    for (; i < E; i += stride) {
        int d = dst[i];
        int pos = atomicAdd(&cursor[d], 1);
        ssrc[pos] = src[i];
    }
}

// ---------------- GEMM: T[n][64] = X[n][K] @ W[K][64] ------------------------
template <int K>
__global__ void k_gemm(const float* __restrict__ X, const float* __restrict__ W,
                       float* __restrict__ T, int n) {
    __shared__ __align__(16) float wl[K * 64];
    __shared__ __align__(16) float xs[16][K];
    int tid = threadIdx.x;
    for (int i = tid; i < K * 64; i += 256) wl[i] = W[i];
    int cg = tid & 15;
    int rs = tid >> 4;
    int ngrp = (n + 15) >> 4;
    for (int grp = blockIdx.x; grp < ngrp; grp += gridDim.x) {
        int row0 = grp * 16;
        __syncthreads();
        for (int i = tid; i < 16 * K; i += 256) {
            int r = i / K, c = i % K;
            int row = row0 + r;
            xs[r][c] = (row < n) ? X[(size_t)row * K + c] : 0.0f;
        }
        __syncthreads();
        float4 acc = {0.f, 0.f, 0.f, 0.f};
#pragma unroll 8
        for (int k = 0; k < K; k++) {
            float xv = xs[rs][k];
            float4 w4 = *reinterpret_cast<const float4*>(&wl[k * 64 + cg * 4]);
            acc.x += xv * w4.x;
            acc.y += xv * w4.y;
            acc.z += xv * w4.z;
            acc.w += xv * w4.w;
        }
        int row = row0 + rs;
        if (row < n) {
            *reinterpret_cast<float4*>(&T[(size_t)row * 64 + cg * 4]) = acc;
        }
    }
}

// ---------------- gather-reduce per dst node (+selfloop+bias+relu) -----------
// one wave per node; lane = channel. FUSE_POOL: atomicAdd into sums[batch[d]].
template <bool FUSE_POOL>
__global__ void k_gather(const int* __restrict__ rowptr, const int* __restrict__ ssrc,
                         const float* __restrict__ dinv, const float* __restrict__ T,
                         const float* __restrict__ bias, const int* __restrict__ batch,
                         float* __restrict__ outbuf, int n) {
    int gtid = blockIdx.x * blockDim.x + threadIdx.x;
    int lane = gtid & 63;
    int w = gtid >> 6;
    int nw = (gridDim.x * blockDim.x) >> 6;
    float bv = bias[lane];
    for (int d = w; d < n; d += nw) {
        int beg = rowptr[d], end = rowptr[d + 1];
        float dd = dinv[d];
        float acc = T[(size_t)d * 64 + lane] * (dd * dd);   // self-loop
        for (int j = beg; j < end; ++j) {
            int s = ssrc[j];
            acc += T[(size_t)s * 64 + lane] * (dinv[s] * dd);
        }
        acc += bv;
        acc = acc > 0.f ? acc : 0.f;
        if (FUSE_POOL) {
            atomicAdd(&outbuf[(size_t)batch[d] * 64 + lane], acc);
        } else {
            outbuf[(size_t)d * 64 + lane] = acc;
        }
    }
}

// ---------------- per-graph node counts ---------------------------------------
__global__ void k_cnt(const int* __restrict__ batch, float* __restrict__ cnt, int n) {
    int i = blockIdx.x * blockDim.x + threadIdx.x;
    if (i < n) atomicAdd(&cnt[batch[i]], 1.0f);
}

// ---------------- head: out[g] = (sums[g]/cnt[g]) @ Wl + bl ------------------
__global__ void k_final(const float* __restrict__ sums, const float* __restrict__ cnt,
                        const float* __restrict__ Wl, const float* __restrict__ bl,
                        float* __restrict__ out) {
    __shared__ float pooled[64];
    int g = blockIdx.x;
    int t = threadIdx.x;
    float c = cnt[g];
    c = c < 1.0f ? 1.0f : c;
    pooled[t] = sums[g * 64 + t] / c;
    __syncthreads();
    if (t < 32) {
        float acc = bl[t];
#pragma unroll 8
        for (int k = 0; k < 64; k++) acc += pooled[k] * Wl[k * 32 + t];
        out[g * 32 + t] = acc;
    }
}

extern "C" void kernel_launch(void* const* d_in, const int* in_sizes, int n_in,
                              void* d_out, int out_size, void* d_ws, size_t ws_size,
                              hipStream_t stream) {
    const float* x = (const float*)d_in[0];
    const int* ei = (const int*)d_in[1];      // [2, E] int32
    const int* batch = (const int*)d_in[2];   // [N] int32
    const float* W1 = (const float*)d_in[4];
    const float* b1 = (const float*)d_in[5];
    const float* W2 = (const float*)d_in[6];
    const float* b2 = (const float*)d_in[7];
    const float* Wl = (const float*)d_in[8];
    const float* bl = (const float*)d_in[9];
    float* out = (float*)d_out;

    const int* esrc = ei;
    const int* edst = ei + NE;

    char* ws = (char*)d_ws;
    size_t off = 0;
    auto alloc = [&](size_t bytes) {
        void* p = ws + off;
        off += (bytes + 255) & ~size_t(255);
        return p;
    };
    int*   degi   = (int*)alloc((size_t)NN * 4);
    float* dinv   = (float*)alloc((size_t)NN * 4);
    int*   rowptr = (int*)alloc((size_t)(NN + 1) * 4);
    int*   bsum   = (int*)alloc((size_t)(NBLK + 1) * 4);
    int*   boff   = (int*)alloc((size_t)(NBLK + 1) * 4);
    int*   ssrc   = (int*)alloc((size_t)NE * 4);        // 12.8 MB
    float* tbuf   = (float*)alloc((size_t)NN * HD * 4); // 25.6 MB
    float* agg    = (float*)alloc((size_t)NN * HD * 4); // 25.6 MB
    float* sums   = (float*)alloc((size_t)NG * HD * 4);
    float* cnt    = (float*)alloc((size_t)NG * 4);
    // scan temps overlay tbuf (dead before gemm1 writes tbuf)
    int* part   = (int*)tbuf;
    int* cursor = (int*)(tbuf + (size_t)NN);

    // 1. CSR build + dinv
    hipMemsetAsync(degi, 0, (size_t)NN * 4, stream);
    k_hist<<<2048, 256, 0, stream>>>(edst, degi, NE);
    k_dinv<<<(NN + 255) / 256, 256, 0, stream>>>(degi, dinv, NN);
    k_scan1<<<NBLK, 1024, 0, stream>>>(degi, part, bsum, NN);
    k_scan2<<<1, 64, 0, stream>>>(bsum, boff, NBLK);
    k_scan3<<<(NN + 256) / 256, 256, 0, stream>>>(part, boff, rowptr, cursor, NN);
    k_bucket<<<2048, 256, 0, stream>>>(esrc, edst, cursor, ssrc, NE);

    // 2. layer 1: t1 = x@W1 ; h1 = relu(gather(t1) + self + b1)  -> agg
    k_gemm<DIN><<<512, 256, 0, stream>>>(x, W1, tbuf, NN);
    k_gather<false><<<2048, 256, 0, stream>>>(rowptr, ssrc, dinv, tbuf, b1, batch, agg, NN);

    // 3. layer 2: t2 = h1@W2 ; h2 rows scattered straight into pool sums
    k_gemm<HD><<<512, 256, 0, stream>>>(agg, W2, tbuf, NN);
    hipMemsetAsync(sums, 0, (size_t)(NG * HD + NG) * 4, stream);  // sums + cnt
    k_cnt<<<(NN + 255) / 256, 256, 0, stream>>>(batch, cnt, NN);
    k_gather<true><<<2048, 256, 0, stream>>>(rowptr, ssrc, dinv, tbuf, b2, batch, sums, NN);

    // 4. head
    k_final<<<NG, 64, 0, stream>>>(sums, cnt, Wl, bl, out);
}

// Round 4
// 1088.408 us; speedup vs baseline: 1.8133x; 1.1855x over previous
//
#include <hip/hip_runtime.h>

#define NN 100000
#define NE 3200000
#define DIN 128
#define HD 64
#define DEMB 32
#define NG 256
#define NBLK ((NN + 1023) / 1024)   // scan blocks = 98

// ---------------- int degree histogram over dst -------------------------------
__global__ void k_hist(const int* __restrict__ dst, int* __restrict__ degi, int E) {
    int i = blockIdx.x * blockDim.x + threadIdx.x;
    int stride = gridDim.x * blockDim.x;
    for (; i < E; i += stride) atomicAdd(&degi[dst[i]], 1);
}

// ---------------- dinv = rsqrt(deg+1) ----------------------------------------
__global__ void k_dinv(const int* __restrict__ degi, float* __restrict__ dinv, int n) {
    int i = blockIdx.x * blockDim.x + threadIdx.x;
    if (i < n) dinv[i] = rsqrtf((float)degi[i] + 1.0f);
}

// ---------------- scan pass 1: per-1024-block exclusive scan ------------------
__global__ __launch_bounds__(1024) void k_scan1(const int* __restrict__ degi,
                                                int* __restrict__ part,
                                                int* __restrict__ bsum, int n) {
    __shared__ int s[1024];
    int t = threadIdx.x;
    int idx = blockIdx.x * 1024 + t;
    int v = (idx < n) ? degi[idx] : 0;
    s[t] = v;
    __syncthreads();
    for (int off = 1; off < 1024; off <<= 1) {
        int add = (t >= off) ? s[t - off] : 0;
        __syncthreads();
        s[t] += add;
        __syncthreads();
    }
    if (idx < n) part[idx] = s[t] - v;          // exclusive
    if (t == 1023) bsum[blockIdx.x] = s[t];     // block total
}

// ---------------- scan pass 2: serial scan of block sums ----------------------
__global__ void k_scan2(const int* __restrict__ bsum, int* __restrict__ boff, int nb) {
    if (threadIdx.x == 0 && blockIdx.x == 0) {
        int acc = 0;
        for (int b = 0; b < nb; b++) { boff[b] = acc; acc += bsum[b]; }
        boff[nb] = acc;   // grand total = E
    }
}

// ---------------- scan pass 3: rowptr + cursor copy ---------------------------
__global__ void k_scan3(const int* __restrict__ part, const int* __restrict__ boff,
                        int* __restrict__ rowptr, int* __restrict__ cursor, int n) {
    int idx = blockIdx.x * blockDim.x + threadIdx.x;
    if (idx < n) {
        int v = part[idx] + boff[idx >> 10];
        rowptr[idx] = v;
        cursor[idx] = v;
    }
    if (idx == n) rowptr[n] = boff[NBLK];
}

// ---------------- counting-sort bucket: ssrc sorted by dst --------------------
__global__ void k_bucket(const int* __restrict__ src, const int* __restrict__ dst,
                         int* __restrict__ cursor, int* __restrict__ ssrc, int E) {
    int i = blockIdx.x * blockDim.x + threadIdx.x;
    int stride = gridDim.x * blockDim.x;
    for (; i < E; i += stride) {
        int d = dst[i];
        int pos = atomicAdd(&cursor[d], 1);
        ssrc[pos] = src[i];
    }
}

// ---------------- GEMM: U[n][64] = (X[n][K] @ W[K][64]) * dinv[row] ----------
template <int K>
__global__ void k_gemm(const float* __restrict__ X, const float* __restrict__ W,
                       const float* __restrict__ dinv, float* __restrict__ U, int n) {
    __shared__ __align__(16) float wl[K * 64];
    __shared__ __align__(16) float xs[16][K];
    int tid = threadIdx.x;
    for (int i = tid; i < K * 64; i += 256) wl[i] = W[i];
    int cg = tid & 15;
    int rs = tid >> 4;
    int ngrp = (n + 15) >> 4;
    for (int grp = blockIdx.x; grp < ngrp; grp += gridDim.x) {
        int row0 = grp * 16;
        __syncthreads();
        for (int i = tid; i < 16 * K; i += 256) {
            int r = i / K, c = i % K;
            int row = row0 + r;
            xs[r][c] = (row < n) ? X[(size_t)row * K + c] : 0.0f;
        }
        __syncthreads();
        float4 acc = {0.f, 0.f, 0.f, 0.f};
#pragma unroll 8
        for (int k = 0; k < K; k++) {
            float xv = xs[rs][k];
            float4 w4 = *reinterpret_cast<const float4*>(&wl[k * 64 + cg * 4]);
            acc.x += xv * w4.x;
            acc.y += xv * w4.y;
            acc.z += xv * w4.z;
            acc.w += xv * w4.w;
        }
        int row = row0 + rs;
        if (row < n) {
            float dv = dinv[row];
            acc.x *= dv; acc.y *= dv; acc.z *= dv; acc.w *= dv;
            *reinterpret_cast<float4*>(&U[(size_t)row * 64 + cg * 4]) = acc;
        }
    }
}

// ---------------- gather-reduce per dst node ----------------------------------
// h[d] = relu(dinv[d] * (sum_{s in N(d)} U[s] + U[d]) + b)
// one wave per node. lane = (g = lane>>4 edge-group, c = lane&15 float4-chunk).
// each global_load_dwordx4 fetches 4 complete 256B rows (1KB/instruction).
template <bool FUSE_POOL>
__global__ void k_gather(const int* __restrict__ rowptr, const int* __restrict__ ssrc,
                         const float* __restrict__ dinv, const float* __restrict__ U,
                         const float* __restrict__ bias, const int* __restrict__ batch,
                         float* __restrict__ outbuf, int n) {
    int gtid = blockIdx.x * blockDim.x + threadIdx.x;
    int lane = gtid & 63;
    int g = lane >> 4;       // edge sub-index within a 4-edge chunk
    int c = lane & 15;       // float4 chunk within the 64-ch row
    int w = gtid >> 6;
    int nw = (gridDim.x * blockDim.x) >> 6;
    float4 bv = *reinterpret_cast<const float4*>(&bias[c * 4]);
    for (int d = w; d < n; d += nw) {
        int beg = rowptr[d], end = rowptr[d + 1];
        float4 acc0 = {0.f, 0.f, 0.f, 0.f};
        float4 acc1 = {0.f, 0.f, 0.f, 0.f};
        int j = beg;
        // 8 edges in flight (two 4-edge groups)
        for (; j + 8 <= end; j += 8) {
            int s0 = ssrc[j + g];
            int s1 = ssrc[j + 4 + g];
            float4 v0 = *reinterpret_cast<const float4*>(&U[(size_t)s0 * 64 + c * 4]);
            float4 v1 = *reinterpret_cast<const float4*>(&U[(size_t)s1 * 64 + c * 4]);
            acc0.x += v0.x; acc0.y += v0.y; acc0.z += v0.z; acc0.w += v0.w;
            acc1.x += v1.x; acc1.y += v1.y; acc1.z += v1.z; acc1.w += v1.w;
        }
        if (j + 4 <= end) {
            int s0 = ssrc[j + g];
            float4 v0 = *reinterpret_cast<const float4*>(&U[(size_t)s0 * 64 + c * 4]);
            acc0.x += v0.x; acc0.y += v0.y; acc0.z += v0.z; acc0.w += v0.w;
            j += 4;
        }
        if (j + g < end) {
            int s1 = ssrc[j + g];
            float4 v1 = *reinterpret_cast<const float4*>(&U[(size_t)s1 * 64 + c * 4]);
            acc1.x += v1.x; acc1.y += v1.y; acc1.z += v1.z; acc1.w += v1.w;
        }
        acc0.x += acc1.x; acc0.y += acc1.y; acc0.z += acc1.z; acc0.w += acc1.w;
        // combine the 4 edge-groups (lanes differing in bits 4,5)
        acc0.x += __shfl_xor(acc0.x, 16); acc0.y += __shfl_xor(acc0.y, 16);
        acc0.z += __shfl_xor(acc0.z, 16); acc0.w += __shfl_xor(acc0.w, 16);
        acc0.x += __shfl_xor(acc0.x, 32); acc0.y += __shfl_xor(acc0.y, 32);
        acc0.z += __shfl_xor(acc0.z, 32); acc0.w += __shfl_xor(acc0.w, 32);
        // self-loop + scale + bias + relu
        float4 ud = *reinterpret_cast<const float4*>(&U[(size_t)d * 64 + c * 4]);
        float dd = dinv[d];
        float4 h;
        h.x = (acc0.x + ud.x) * dd + bv.x;
        h.y = (acc0.y + ud.y) * dd + bv.y;
        h.z = (acc0.z + ud.z) * dd + bv.z;
        h.w = (acc0.w + ud.w) * dd + bv.w;
        h.x = h.x > 0.f ? h.x : 0.f;
        h.y = h.y > 0.f ? h.y : 0.f;
        h.z = h.z > 0.f ? h.z : 0.f;
        h.w = h.w > 0.f ? h.w : 0.f;
        if (FUSE_POOL) {
            if (g == 0) {
                float* sp = &outbuf[(size_t)batch[d] * 64 + c * 4];
                atomicAdd(sp + 0, h.x);
                atomicAdd(sp + 1, h.y);
                atomicAdd(sp + 2, h.z);
                atomicAdd(sp + 3, h.w);
            }
        } else {
            if (g == 0) {
                *reinterpret_cast<float4*>(&outbuf[(size_t)d * 64 + c * 4]) = h;
            }
        }
    }
}

// ---------------- per-graph node counts ---------------------------------------
__global__ void k_cnt(const int* __restrict__ batch, float* __restrict__ cnt, int n) {
    int i = blockIdx.x * blockDim.x + threadIdx.x;
    if (i < n) atomicAdd(&cnt[batch[i]], 1.0f);
}

// ---------------- head: out[g] = (sums[g]/cnt[g]) @ Wl + bl ------------------
__global__ void k_final(const float* __restrict__ sums, const float* __restrict__ cnt,
                        const float* __restrict__ Wl, const float* __restrict__ bl,
                        float* __restrict__ out) {
    __shared__ float pooled[64];
    int g = blockIdx.x;
    int t = threadIdx.x;
    float c = cnt[g];
    c = c < 1.0f ? 1.0f : c;
    pooled[t] = sums[g * 64 + t] / c;
    __syncthreads();
    if (t < 32) {
        float acc = bl[t];
#pragma unroll 8
        for (int k = 0; k < 64; k++) acc += pooled[k] * Wl[k * 32 + t];
        out[g * 32 + t] = acc;
    }
}

extern "C" void kernel_launch(void* const* d_in, const int* in_sizes, int n_in,
                              void* d_out, int out_size, void* d_ws, size_t ws_size,
                              hipStream_t stream) {
    const float* x = (const float*)d_in[0];
    const int* ei = (const int*)d_in[1];      // [2, E] int32
    const int* batch = (const int*)d_in[2];   // [N] int32
    const float* W1 = (const float*)d_in[4];
    const float* b1 = (const float*)d_in[5];
    const float* W2 = (const float*)d_in[6];
    const float* b2 = (const float*)d_in[7];
    const float* Wl = (const float*)d_in[8];
    const float* bl = (const float*)d_in[9];
    float* out = (float*)d_out;

    const int* esrc = ei;
    const int* edst = ei + NE;

    char* ws = (char*)d_ws;
    size_t off = 0;
    auto alloc = [&](size_t bytes) {
        void* p = ws + off;
        off += (bytes + 255) & ~size_t(255);
        return p;
    };
    int*   degi   = (int*)alloc((size_t)NN * 4);
    float* dinv   = (float*)alloc((size_t)NN * 4);
    int*   rowptr = (int*)alloc((size_t)(NN + 1) * 4);
    int*   bsum   = (int*)alloc((size_t)(NBLK + 1) * 4);
    int*   boff   = (int*)alloc((size_t)(NBLK + 1) * 4);
    int*   ssrc   = (int*)alloc((size_t)NE * 4);        // 12.8 MB
    float* tbuf   = (float*)alloc((size_t)NN * HD * 4); // 25.6 MB
    float* agg    = (float*)alloc((size_t)NN * HD * 4); // 25.6 MB
    float* sums   = (float*)alloc((size_t)NG * HD * 4);
    float* cnt    = (float*)alloc((size_t)NG * 4);
    // scan temps overlay tbuf (dead before gemm1 writes tbuf)
    int* part   = (int*)tbuf;
    int* cursor = (int*)(tbuf + (size_t)NN);

    // 1. CSR build + dinv
    hipMemsetAsync(degi, 0, (size_t)NN * 4, stream);
    k_hist<<<2048, 256, 0, stream>>>(edst, degi, NE);
    k_dinv<<<(NN + 255) / 256, 256, 0, stream>>>(degi, dinv, NN);
    k_scan1<<<NBLK, 1024, 0, stream>>>(degi, part, bsum, NN);
    k_scan2<<<1, 64, 0, stream>>>(bsum, boff, NBLK);
    k_scan3<<<(NN + 256) / 256, 256, 0, stream>>>(part, boff, rowptr, cursor, NN);
    k_bucket<<<2048, 256, 0, stream>>>(esrc, edst, cursor, ssrc, NE);

    // 2. layer 1: U1 = (x@W1)*dinv ; h1 = relu(dinv*(gather+self) + b1) -> agg
    k_gemm<DIN><<<512, 256, 0, stream>>>(x, W1, dinv, tbuf, NN);
    k_gather<false><<<2048, 256, 0, stream>>>(rowptr, ssrc, dinv, tbuf, b1, batch, agg, NN);

    // 3. layer 2: U2 = (h1@W2)*dinv ; h2 rows scattered straight into pool sums
    k_gemm<HD><<<512, 256, 0, stream>>>(agg, W2, dinv, tbuf, NN);
    hipMemsetAsync(sums, 0, (size_t)(NG * HD + NG) * 4, stream);  // sums + cnt
    k_cnt<<<(NN + 255) / 256, 256, 0, stream>>>(batch, cnt, NN);
    k_gather<true><<<2048, 256, 0, stream>>>(rowptr, ssrc, dinv, tbuf, b2, batch, sums, NN);

    // 4. head
    k_final<<<NG, 64, 0, stream>>>(sums, cnt, Wl, bl, out);
}